// Round 9
// baseline (1144.085 us; speedup 1.0000x reference)
//
#include <hip/hip_runtime.h>
#include <math.h>

typedef __bf16 bf16_t;
typedef __bf16 bf16x8 __attribute__((ext_vector_type(8)));
typedef float f32x4 __attribute__((ext_vector_type(4)));

#define H    8
#define SD   17
#define HD   240
#define KIN  257
#define KQP  288      // padded K for projections
#define SCOL 256      // s-block width (8 x 32)
#define DTOT 2176     // 256 + 1920
#define NTOT 30000
#define CHS  15000    // source chunk
#define NCS  2
#define CHPS 15360    // CHS padded to 256 and to KSPLIT*32 (=512 mult)
#define CHQ  15000    // query chunk
#define NCQ  2
#define YQROWS 15104  // Yq rows incl. staging pad
#define XROWS 15360   // xcb rows incl. staging pad (kv grid covers CHPS; qproj reads to 15104)
#define KSPLIT 16
#define OSPLIT 4      // opre K-split
#define OSLAB (15104L * 257)

#define BK   32       // LDS row stride = BK halves (NO pad: global_load_lds needs contiguous lane order)

__device__ __forceinline__ float phi_elu1(float x) {
    return x > 0.f ? x + 1.f : __expf(x);
}

// bijective XCD-aware swizzle (m204 form): contiguous wg chunk per XCD
__device__ __forceinline__ int xcd_swz(int orig, int nwg) {
    int q = nwg >> 3, r = nwg & 7;
    int xcd = orig & 7, off = orig >> 3;
    return (xcd < r ? xcd * (q + 1) : r * (q + 1) + (xcd - r) * q) + off;
}

// async 16B global -> LDS (DMA, no VGPR round-trip). dest must be wave-uniform base + lane*16.
__device__ __forceinline__ void gl_lds16(const bf16_t* g, bf16_t* l) {
    __builtin_amdgcn_global_load_lds(
        (const __attribute__((address_space(1))) void*)g,
        (__attribute__((address_space(3))) void*)l, 16, 0, 0);
}

// counted vmcnt wait (T4): leave N loads in flight; sched_barrier pins ordering
template<int N> __device__ __forceinline__ void waitvm() {
    asm volatile("s_waitcnt vmcnt(%0)" :: "n"(N) : "memory");
    __builtin_amdgcn_sched_barrier(0);
}

struct GemmP {
    const bf16_t* A; long lda; long aHead;
    const bf16_t* B; long ldb; long bHead;
    float* Cf; bf16_t* Cb; long ldc; long cHead; int atomicC; // 0=store 1=atomicAdd 3=per-z slab store
    int M, N, K, nSplit;
};

// C[m,n] = sum_k A[m,k]*B[n,k]; bf16 MFMA, f32 acc. K (per split) mult of 32.
// NBUF=3: depth-2 prefetch with counted vmcnt (for deep K-loops).
// NBUF=2: classic double-buffer (49KB LDS cap at 384-row tiles -> 3 blocks/CU).
// One raw s_barrier per K-step, XOR chunk-swizzle on LDS (both sides).
// NOTE: no staging bounds checks — operand buffers MUST be allocated/padded to
// tile-multiple rows (garbage rows only feed discarded C rows/cols; K-pad cols zeroed).
template<int TBM, int TBN, int NBUF = 3>
__global__ void __launch_bounds__(256)
k_mfma_nt(GemmP p)
{
    constexpr int FI = TBM / 32;
    constexpr int FJ = TBN / 32;
    constexpr int LPT = TBM / 64 + TBN / 64;   // gl_lds16 per thread per stage
    __shared__ bf16_t As[NBUF][TBM * BK];
    __shared__ bf16_t Bs[NBUF][TBN * BK];
    const int t  = threadIdx.x;
    const int z  = blockIdx.z;
    const int h  = z / p.nSplit;
    const int sp = z % p.nSplit;
    const int kWin = p.K / p.nSplit;
    const int k0   = sp * kWin;
    const int nwg  = gridDim.x * gridDim.y;
    const int wg   = xcd_swz(blockIdx.y * gridDim.x + blockIdx.x, nwg);
    const int m0 = (wg % gridDim.x) * TBM;
    const int n0 = (wg / gridDim.x) * TBN;
    const bf16_t* A = p.A + (long)h * p.aHead;
    const bf16_t* B = p.B + (long)h * p.bHead;

    const int lr = t >> 2;     // staging row within 64-group
    const int lc = t & 3;      // 16B chunk
    const int wid  = t >> 6;
    const int lane = t & 63;
    const int wm = (wid >> 1) * (TBM / 2);
    const int wn = (wid & 1) * (TBN / 2);
    const int fr = lane & 15;
    const int fq = lane >> 4;

    f32x4 acc[FI][FJ] = {};

    // pre-swizzled global k-chunk: LDS slot (row, c) holds global chunk c ^ ((row>>1)&3)
    auto stage = [&](int buf, int kb) {
        const int gk = kb + ((lc ^ ((lr >> 1) & 3)) << 3);
#pragma unroll
        for (int it = 0; it < TBM / 64; ++it)
            gl_lds16(A + (long)(m0 + lr + it * 64) * p.lda + gk, &As[buf][it * 2048 + t * 8]);
#pragma unroll
        for (int it = 0; it < TBN / 64; ++it)
            gl_lds16(B + (long)(n0 + lr + it * 64) * p.ldb + gk, &Bs[buf][it * 2048 + t * 8]);
    };

    auto compute = [&](int cur) {
        bf16x8 af[FI], bfr[FJ];
#pragma unroll
        for (int i = 0; i < FI; ++i) {
            const int row = wm + i * 16 + fr;
            af[i] = *(const bf16x8*)(&As[cur][row * BK + ((fq ^ ((row >> 1) & 3)) << 3)]);
        }
#pragma unroll
        for (int j = 0; j < FJ; ++j) {
            const int row = wn + j * 16 + fr;
            bfr[j] = *(const bf16x8*)(&Bs[cur][row * BK + ((fq ^ ((row >> 1) & 3)) << 3)]);
        }
#pragma unroll
        for (int i = 0; i < FI; ++i)
#pragma unroll
            for (int j = 0; j < FJ; ++j)
                acc[i][j] = __builtin_amdgcn_mfma_f32_16x16x32_bf16(af[i], bfr[j], acc[i][j], 0, 0, 0);
    };

    const int nSteps = kWin / BK;
    if constexpr (NBUF == 3) {
        stage(0, k0);
        if (nSteps > 1) stage(1, k0 + BK);
        int cur = 0, pf = 2;
#pragma unroll 1
        for (int s = 0; s < nSteps; ++s) {
            if (s + 1 < nSteps) waitvm<LPT>();     // cur's loads landed; next stays in flight
            else                waitvm<0>();
            __builtin_amdgcn_s_barrier();          // all waves: cur staged, prev reads done
            __builtin_amdgcn_sched_barrier(0);
            if (s + 2 < nSteps) {                  // overwrite buf read 2 iters ago (safe past barrier)
                stage(pf, k0 + (s + 2) * BK);
                pf = (pf == 2) ? 0 : pf + 1;
            }
            compute(cur);
            cur = (cur == 2) ? 0 : cur + 1;
        }
    } else {
        stage(0, k0);
        int cur = 0;
#pragma unroll 1
        for (int s = 0; s < nSteps; ++s) {
            waitvm<0>();                           // cur's loads landed (only stage in flight)
            __builtin_amdgcn_s_barrier();          // all waves: prev reads done
            __builtin_amdgcn_sched_barrier(0);
            if (s + 1 < nSteps) stage(cur ^ 1, k0 + (s + 1) * BK);  // overlap w/ compute
            compute(cur);
            cur ^= 1;
        }
    }

    float*  Cf = 0; bf16_t* Cb = 0;
    if (p.atomicC == 3)      Cf = p.Cf + (long)z * p.cHead;      // per-split slab, exclusive store
    else if (p.Cf)           Cf = p.Cf + (long)h * p.cHead;
    else                     Cb = p.Cb + (long)h * p.cHead;
#pragma unroll
    for (int i = 0; i < FI; ++i) {
#pragma unroll
        for (int r = 0; r < 4; ++r) {
            const int m = m0 + wm + i * 16 + fq * 4 + r;
            if (m >= p.M) continue;
#pragma unroll
            for (int j = 0; j < FJ; ++j) {
                const int n = n0 + wn + j * 16 + fr;
                if (n >= p.N) continue;
                const float v = acc[i][j][r];
                const long idx = (long)m * p.ldc + n;
                if (p.atomicC == 1)      atomicAdd(&Cf[idx], v);
                else if (Cf)             Cf[idx] = v;            // modes 0 and 3
                else                     Cb[idx] = (bf16_t)v;
            }
        }
    }
}

// KV projection, TRANSPOSED output: C[col][row] = sum_k Wkvb[col][k]*xcb[row][k].
// Block tile 128x256, wave tile 64x128 (FI=4, FJ=8): 1.6x arithmetic intensity per
// LDS byte vs 64x64. 2-buffer double-buffer keeps LDS at 49KB -> 3 blocks/CU.
// Writes directly into Tk/Tv [2176][CHPS]. Grid y covers ALL CHPS cols (pad cols
// zeroed). K-h cols (SCOL..DTOT): phi on f32 acc + ksum column-sum via shuffle+atomic.
__global__ void __launch_bounds__(256)
k_mfma_kv(const bf16_t* __restrict__ A, const bf16_t* __restrict__ Bsrc,
          bf16_t* __restrict__ Tk, bf16_t* __restrict__ Tv,
          float* __restrict__ ksum, int nRows)
{
    constexpr int FI = 4, FJ = 8;
    __shared__ bf16_t As[2][128 * BK];
    __shared__ bf16_t Bs[2][256 * BK];
    const int t = threadIdx.x;
    const int nwg = gridDim.x * gridDim.y;
    const int wg  = xcd_swz(blockIdx.y * gridDim.x + blockIdx.x, nwg);
    const int m0 = (wg % gridDim.x) * 128;   // output (weight-col) tile
    const int n0 = (wg / gridDim.x) * 256;   // source-row tile

    const int lr = t >> 2;
    const int lc = t & 3;
    const int wid  = t >> 6;
    const int lane = t & 63;
    const int wm = (wid >> 1) * 64;
    const int wn = (wid & 1) * 128;
    const int fr = lane & 15;
    const int fq = lane >> 4;

    f32x4 acc[FI][FJ] = {};

    auto stage = [&](int buf, int kb) {
        const int gk = kb + ((lc ^ ((lr >> 1) & 3)) << 3);
        gl_lds16(A + (long)(m0 + lr)      * KQP + gk, &As[buf][t * 8]);
        gl_lds16(A + (long)(m0 + lr + 64) * KQP + gk, &As[buf][2048 + t * 8]);
#pragma unroll
        for (int it = 0; it < 4; ++it)
            gl_lds16(Bsrc + (long)(n0 + lr + it * 64) * KQP + gk, &Bs[buf][it * 2048 + t * 8]);
    };

    constexpr int nSteps = KQP / BK;   // 9
    stage(0, 0);
    int cur = 0;
#pragma unroll 1
    for (int s = 0; s < nSteps; ++s) {
        waitvm<0>();
        __builtin_amdgcn_s_barrier();
        __builtin_amdgcn_sched_barrier(0);
        if (s + 1 < nSteps) stage(cur ^ 1, (s + 1) * BK);
        bf16x8 af[FI], bfr[FJ];
#pragma unroll
        for (int i = 0; i < FI; ++i) {
            const int row = wm + i * 16 + fr;
            af[i] = *(const bf16x8*)(&As[cur][row * BK + ((fq ^ ((row >> 1) & 3)) << 3)]);
        }
#pragma unroll
        for (int j = 0; j < FJ; ++j) {
            const int row = wn + j * 16 + fr;
            bfr[j] = *(const bf16x8*)(&Bs[cur][row * BK + ((fq ^ ((row >> 1) & 3)) << 3)]);
        }
#pragma unroll
        for (int i = 0; i < FI; ++i)
#pragma unroll
            for (int j = 0; j < FJ; ++j)
                acc[i][j] = __builtin_amdgcn_mfma_f32_16x16x32_bf16(af[i], bfr[j], acc[i][j], 0, 0, 0);
        cur ^= 1;
    }

    const bool isKh = (m0 >= SCOL) && (m0 < DTOT);
    bf16_t* outB = (m0 < DTOT) ? (Tk + (long)m0 * CHPS)
                               : (Tv + (long)(m0 - DTOT) * CHPS);
#pragma unroll
    for (int i = 0; i < FI; ++i) {
#pragma unroll
        for (int r = 0; r < 4; ++r) {
            const int ml = wm + i * 16 + fq * 4 + r;    // local output row (weight col)
            bf16_t* row = outB + (long)ml * CHPS;
            float kacc = 0.f;
#pragma unroll
            for (int j = 0; j < FJ; ++j) {
                const int n = n0 + wn + j * 16 + fr;    // source row (output col)
                float v = 0.f;
                if (n < nRows) {
                    v = acc[i][j][r];
                    if (isKh) { v = phi_elu1(v); kacc += v; }
                }
                row[n] = (bf16_t)v;
            }
            if (isKh) {
                kacc += __shfl_xor(kacc, 1);
                kacc += __shfl_xor(kacc, 2);
                kacc += __shfl_xor(kacc, 4);
                kacc += __shfl_xor(kacc, 8);
                if (fr == 0) atomicAdd(&ksum[m0 + ml], kacc);
            }
        }
    }
}

// s-part post, transposed layout: per (source row n, head h) normalize the 17-wide
// K-s / V-s blocks in place (Tk/Tv rows h*32..h*32+16, col n), phi the K side, and
// accumulate ksum-s column sums. Loads/stores are lane-coalesced over n.
__global__ void __launch_bounds__(256)
k_post_kv_t(bf16_t* __restrict__ Tk, bf16_t* __restrict__ Tv,
            float* __restrict__ ksum, int rows)
{
    const int h = blockIdx.y;
    const int n = blockIdx.x * 256 + threadIdx.x;
    const int lane = threadIdx.x & 63;
    const bool act = n < rows;
    float kv[SD], vv[SD];
    float sk = 0.f, sv = 0.f;
#pragma unroll
    for (int j = 0; j < SD; ++j) {
        kv[j] = act ? (float)Tk[(long)(h * 32 + j) * CHPS + n] : 0.f;
        vv[j] = act ? (float)Tv[(long)(h * 32 + j) * CHPS + n] : 0.f;
        sk += kv[j] * kv[j];
        sv += vv[j] * vv[j];
    }
    const float ik = 1.f / (sqrtf(sk) + 1e-8f);
    const float iv = 1.f / (sqrtf(sv) + 1e-8f);
#pragma unroll
    for (int j = 0; j < SD; ++j) {
        float pk = act ? phi_elu1(kv[j] * ik) : 0.f;
        if (act) {
            Tk[(long)(h * 32 + j) * CHPS + n] = (bf16_t)pk;
            Tv[(long)(h * 32 + j) * CHPS + n] = (bf16_t)(vv[j] * iv);
        }
        float s = pk;
#pragma unroll
        for (int off = 32; off > 0; off >>= 1) s += __shfl_down(s, off);
        if (lane == 0) atomicAdd(&ksum[h * 32 + j], s);
    }
}

// f32 [rows][257] -> bf16 [rows][288] zero-padded, bf16x8 stores
__global__ void k_cast_pad(const float* __restrict__ in, bf16_t* __restrict__ out, long rows)
{
    long i = (long)blockIdx.x * 256 + threadIdx.x;   // 8-elem chunk id
    if (i >= rows * (KQP / 8)) return;
    long r = i / (KQP / 8); int c8 = (int)(i - r * (KQP / 8)) * 8;
    const float* ip = in + r * KIN + c8;
    bf16x8 o;
#pragma unroll
    for (int j = 0; j < 8; ++j)
        o[j] = (c8 + j < KIN) ? (bf16_t)ip[j] : (bf16_t)0.f;
    *(bf16x8*)(out + r * KQP + c8) = o;
}

// Wq/Wk/Wv [H][257][257] -> head-split padded [2176][288]
__global__ void k_prep_proj(const float* __restrict__ W, bf16_t* __restrict__ dst)
{
    long i = (long)blockIdx.x * 256 + threadIdx.x;
    if (i >= (long)DTOT * KQP) return;
    int r = (int)(i / KQP), k = (int)(i % KQP);
    float v = 0.f;
    if (r < SCOL) {
        int h = r >> 5, j = r & 31;
        if (j < SD && k < KIN) v = W[((long)h * 257 + j) * 257 + k];
    } else {
        int rr = r - SCOL;
        int h = rr / HD, j = rr % HD;
        if (k < KIN) v = W[((long)h * 257 + SD + j) * 257 + k];
    }
    dst[i] = (bf16_t)v;
}

// Ws [17][136] -> Wsb [64][256] head-split 32-padded, zero rows >= 17
__global__ void k_prep_ws(const float* __restrict__ ws, bf16_t* __restrict__ out)
{
    int o = blockIdx.x; int t = threadIdx.x;
    int h = t >> 5, j = t & 31;
    float v = 0.f;
    if (o < SD && j < SD) v = ws[o * (H * SD) + h * SD + j];
    out[o * 256 + t] = (bf16_t)v;
}

// Wh [240][1920] -> Whb [256][2048] head-split 256-padded, zero rows >= 240
__global__ void k_prep_wh(const float* __restrict__ wh, bf16_t* __restrict__ out)
{
    long i = (long)blockIdx.x * 256 + threadIdx.x;
    if (i >= 256L * 2048) return;
    int o = (int)(i / 2048), c = (int)(i % 2048);
    int h = c >> 8, j = c & 255;
    float v = 0.f;
    if (o < 240 && j < HD) v = wh[(long)o * 1920 + h * HD + j];
    out[i] = (bf16_t)v;
}

// post for Q: phi + s-norm, compute den vs ksum, scale by 1/(den+eps) IN PLACE.
// h-part vectorized: 240 = 30 lanes x bf16x8.
__global__ void __launch_bounds__(256)
k_post_q(bf16_t* __restrict__ Yq, const float* __restrict__ ksum, int rows)
{
    const int wid  = blockIdx.x * 4 + (threadIdx.x >> 6);
    const int lane = threadIdx.x & 63;
    const int n = wid >> 3, h = wid & 7;
    if (n >= rows) return;
    bf16_t* row = Yq + (long)n * DTOT;
    float qv = (lane < SD) ? (float)row[h * 32 + lane] : 0.f;
    float sq = qv * qv;
#pragma unroll
    for (int off = 32; off > 0; off >>= 1) sq += __shfl_down(sq, off);
    sq = __shfl(sq, 0);
    const float iq = 1.f / (sqrtf(sq) + 1e-8f);
    float pvs = (lane < SD) ? phi_elu1(qv * iq) : 0.f;
    float ds = (lane < SD) ? pvs * ksum[h * 32 + lane] : 0.f;
    float ph[8];
    float dh = 0.f;
    if (lane < 30) {
        bf16x8 hv8 = *(const bf16x8*)(row + SCOL + h * HD + lane * 8);
        const float* kp = ksum + SCOL + h * HD + lane * 8;
#pragma unroll
        for (int i = 0; i < 8; ++i) {
            ph[i] = phi_elu1((float)hv8[i]);
            dh += ph[i] * kp[i];
        }
    }
#pragma unroll
    for (int off = 32; off > 0; off >>= 1) {
        ds += __shfl_down(ds, off);
        dh += __shfl_down(dh, off);
    }
    ds = __shfl(ds, 0); dh = __shfl(dh, 0);
    const float ss = 1.f / (ds + 1e-6f);
    const float sh = 1.f / (dh + 1e-8f);
    if (lane < 32)
        row[h * 32 + lane] = (bf16_t)((lane < SD) ? pvs * ss : 0.f);
    if (lane < 30) {
        bf16x8 o8;
#pragma unroll
        for (int i = 0; i < 8; ++i) o8[i] = (bf16_t)(ph[i] * sh);
        *(bf16x8*)(row + SCOL + h * HD + lane * 8) = o8;
    }
}

// f32 -> bf16
__global__ void k_castf(const float* __restrict__ in, bf16_t* __restrict__ out, long n)
{
    long i = (long)blockIdx.x * 256 + threadIdx.x;
    if (i < n) out[i] = (bf16_t)in[i];
}

// final epilogue: sums the OSPLIT K-split slabs of opre, then normalizes
__global__ void __launch_bounds__(256)
k_finalize(const float* __restrict__ pre, float* __restrict__ outp, int rows)
{
    int n    = blockIdx.x * 4 + (threadIdx.x >> 6);
    int lane = threadIdx.x & 63;
    if (n >= rows) return;
    const float* rp = pre + (long)n * 257;
    float* op = outp + (long)n * 257;
    float sv = 0.f;
    if (lane < SD) {
#pragma unroll
        for (int s = 0; s < OSPLIT; ++s) sv += rp[s * OSLAB + lane];
    }
    float ssq = sv * sv;
    float hv[4];
    float hsq = 0.f;
#pragma unroll
    for (int i = 0; i < 4; ++i) {
        int o = lane + 64 * i;
        float v = 0.f;
        if (o < HD) {
#pragma unroll
            for (int s = 0; s < OSPLIT; ++s) v += rp[s * OSLAB + SD + o];
        }
        hv[i] = v;
        hsq += v * v;
    }
#pragma unroll
    for (int off = 32; off > 0; off >>= 1) {
        ssq += __shfl_down(ssq, off);
        hsq += __shfl_down(hsq, off);
    }
    ssq = __shfl(ssq, 0); hsq = __shfl(hsq, 0);
    float an_raw = sqrtf(ssq);
    float bn_raw = sqrtf(hsq);
    float an = an_raw + 1e-8f;
    float bn = bn_raw + 1e-8f;
    bool ma = an > 1e6f;
    bool mb = bn > 1e6f;
    float an_c = fminf(an, 1e6f);
    float bn_c = fminf(bn, 1e6f);
    float na = ma ? (an_raw / an_c) : an_raw;
    na = fmaxf(na, 1e-12f);
    float inv_s = (ma ? (1.f / an_c) : 1.f) / na;
    float bt = sqrtf(bn_c * bn_c + 1.0f);
    float nb = fmaxf(bn_raw / bn_c, 1e-12f);
    float scale_b = 1e6f / (bn_c * nb);
    if (lane < SD) op[lane] = bt * (sv * inv_s);
#pragma unroll
    for (int i = 0; i < 4; ++i) {
        int o = lane + 64 * i;
        if (o < HD) op[SD + o] = mb ? hv[i] * scale_b : hv[i];
    }
}

static inline long alup(long b) { return (b + 255) & ~255L; }

extern "C" void kernel_launch(void* const* d_in, const int* in_sizes, int n_in,
                              void* d_out, int out_size, void* d_ws, size_t ws_size,
                              hipStream_t stream)
{
    const float* query  = (const float*)d_in[0];
    const float* source = (const float*)d_in[1];
    const float* Wq     = (const float*)d_in[2];
    const float* Wk     = (const float*)d_in[3];
    const float* Wv     = (const float*)d_in[4];
    const float* Ws     = (const float*)d_in[5];
    const float* Wh     = (const float*)d_in[6];
    float* out = (float*)d_out;

    // ---- workspace (~152 MB; proven ws >= ~205 MB). All GEMM operands padded to
    // tile-multiple rows because async staging has no bounds checks. ----
    char* p = (char*)d_ws;
    auto alloc = [&](long b) { char* r = p; p += alup(b); return r; };
    bf16_t* Wkvb = (bf16_t*)alloc(2L * DTOT * KQP * 2);       // [4352][288]
    bf16_t* Wqb  = (bf16_t*)alloc((long)DTOT * KQP * 2);      // [2176][288]
    bf16_t* Wsb  = (bf16_t*)alloc(64L * 256 * 2);             // [64][256] zero-padded
    bf16_t* Whb  = (bf16_t*)alloc(256L * 2048 * 2);           // [256][2048] zero-padded
    bf16_t* Gfull= (bf16_t*)alloc(384L * DTOT * 2);           // [384][2176] zeroed (192-tile staging)
    float*  ktvF = (float*) alloc((8L * HD * 256 + 8L * 32 * 32) * 4);
    float*  ksum = (float*) alloc((long)DTOT * 4);            // contiguous after ktvF
    bf16_t* ktvB = (bf16_t*)alloc((8L * HD * 256 + 8L * 32 * 32) * 2);
    bf16_t* xcb  = (bf16_t*)alloc((long)XROWS * KQP * 2);     // [15360][288]
    // union: source {Tk,Tv(+16 slack rows)} / query {Yq(15104 rows), opre slabs}
    long tkBytes = (long)DTOT * CHPS * 2;
    char* ub = alloc(2 * tkBytes + 16L * CHPS * 2);
    bf16_t* Tk  = (bf16_t*)ub;
    bf16_t* Tv  = Tk + (long)DTOT * CHPS;
    bf16_t* Yq  = Tk;                                         // [15104][2176]
    float*  opre= (float*)(Yq + (long)YQROWS * DTOT);         // OSPLIT slabs [15104][257] f32

    float*  ktvHf = ktvF;
    float*  ktvSf = ktvF + 8L * HD * 256;
    bf16_t* ktvHb = ktvB;
    bf16_t* ktvSb = ktvB + 8L * HD * 256;

    (void)hipMemsetAsync(ktvF, 0, (char*)(ksum + DTOT) - (char*)ktvF, stream);
    (void)hipMemsetAsync(Gfull, 0, 384L * DTOT * 2, stream);

    // ---- weight prep ----
    const unsigned gw = (unsigned)(((long)DTOT * KQP + 255) / 256);
    k_prep_proj<<<gw, 256, 0, stream>>>(Wk, Wkvb);
    k_prep_proj<<<gw, 256, 0, stream>>>(Wv, Wkvb + (long)DTOT * KQP);
    k_prep_proj<<<gw, 256, 0, stream>>>(Wq, Wqb);
    k_prep_ws<<<64, 256, 0, stream>>>(Ws, Wsb);
    k_prep_wh<<<(unsigned)((256L * 2048 + 255) / 256), 256, 0, stream>>>(Wh, Whb);

    GemmP g;

    // ---------------- source phase (2 chunks of 15000) ----------------
    for (int c = 0; c < NCS; ++c) {
        const float* src = source + (long)c * CHS * KIN;
        k_cast_pad<<<(unsigned)(((long)CHS * (KQP / 8) + 255) / 256), 256, 0, stream>>>(src, xcb, CHS);
        // Tk/Tv = (xcb @ Wkvb^T)^T written directly, phi+ksum fused for K-h.
        // grid y covers all CHPS cols (pad cols zeroed here).
        k_mfma_kv<<<dim3((2 * DTOT) / 128, CHPS / 256, 1), 256, 0, stream>>>(
            Wkvb, xcb, Tk, Tv, ksum, CHS);
        k_post_kv_t<<<dim3((CHS + 255) / 256, H), 256, 0, stream>>>(Tk, Tv, ksum, CHS);
        // ktvH_h[k'][v] += sum_n Tk_h[k'][n]*Tv_h[v][n]  (K = 15360, 30 steps/split)
        g = { Tk + (long)SCOL * CHPS, CHPS, (long)HD * CHPS,
              Tv + (long)SCOL * CHPS, CHPS, (long)HD * CHPS,
              ktvHf, 0, 256, (long)HD * 256, 1,  HD, HD, CHPS, KSPLIT };
        k_mfma_nt<128, 128><<<dim3(2, 2, H * KSPLIT), 256, 0, stream>>>(g);
        g = { Tk, CHPS, 32L * CHPS,  Tv, CHPS, 32L * CHPS,
              ktvSf, 0, 32, 32L * 32, 1,  32, 32, CHPS, KSPLIT };
        k_mfma_nt<64, 64><<<dim3(1, 1, H * KSPLIT), 256, 0, stream>>>(g);
    }
    k_castf<<<(unsigned)((8L * (HD * 256 + 32 * 32) + 255) / 256), 256, 0, stream>>>(
        ktvF, ktvB, 8L * (HD * 256 + 32 * 32));

    // ---- fold ktv into output weights: Gfull[o][k] ----
    g = { Wsb, 256, 32,  ktvSb, 32, 32L * 32,  0, Gfull, DTOT, 32, 0,
          SD, 32, 32, 1 };
    k_mfma_nt<64, 64><<<dim3(1, 1, H), 256, 0, stream>>>(g);
    g = { Whb, 2048, 256,  ktvHb, 256, (long)HD * 256,
          0, Gfull + 17L * DTOT + SCOL, DTOT, HD, 0,
          HD, HD, 256, 1 };
    k_mfma_nt<64, 64><<<dim3(4, 4, H), 256, 0, stream>>>(g);

    // ---------------- query phase (2 chunks of 15000) ----------------
    for (int c = 0; c < NCQ; ++c) {
        const float* qsrc = query + (long)c * CHQ * KIN;
        float* orow = out + (long)c * CHQ * 257;
        k_cast_pad<<<(unsigned)(((long)CHQ * (KQP / 8) + 255) / 256), 256, 0, stream>>>(qsrc, xcb, CHQ);
        // Yq = xcb @ Wqb^T : 256x128 tile, wave 128x64, 2-buffer (49KB)
        g = { xcb, KQP, 0,  Wqb, KQP, 0,  0, Yq, DTOT, 0, 0,
              CHQ, DTOT, KQP, 1 };
        k_mfma_nt<256, 128, 2><<<dim3((CHQ + 255) / 256, DTOT / 128, 1), 256, 0, stream>>>(g);
        k_post_q<<<(CHQ * H) / 4, 256, 0, stream>>>(Yq, ksum, CHQ);
        // opre slabs = Yq_scaled @ Gfull^T, K split into OSPLIT windows (exclusive slab stores)
        g = { Yq, DTOT, 0,  Gfull, DTOT, 0,  opre, 0, 257, OSLAB, 3,
              CHQ, 257, DTOT, OSPLIT };
        k_mfma_nt<64, 192><<<dim3((CHQ + 63) / 64, 2, OSPLIT), 256, 0, stream>>>(g);
        k_finalize<<<(CHQ + 3) / 4, 256, 0, stream>>>(opre, orow, CHQ);
    }
}

// Round 11
// 1028.524 us; speedup vs baseline: 1.1124x; 1.1124x over previous
//
#include <hip/hip_runtime.h>
#include <math.h>

typedef __bf16 bf16_t;
typedef __bf16 bf16x8 __attribute__((ext_vector_type(8)));
typedef float f32x4 __attribute__((ext_vector_type(4)));

#define H    8
#define SD   17
#define HD   240
#define KIN  257
#define KQP  288      // padded K for projections
#define SCOL 256      // s-block width (8 x 32)
#define DTOT 2176     // 256 + 1920
#define NTOT 30000
#define CHS  15000    // source chunk
#define NCS  2
#define CHPS 15360    // CHS padded to 256 and to KSPLIT*32 (=512 mult)
#define CHQ  15000    // query chunk
#define NCQ  2
#define YQROWS 15104  // Yq rows incl. staging pad
#define XROWS 15360   // xcb rows incl. staging pad (kv grid covers CHPS; qproj reads to 15104)
#define KSPLIT 16
#define OSPLIT 4      // opre K-split
#define OSLAB (15104L * 257)

#define BK   32       // LDS row stride = BK halves (NO pad: global_load_lds needs contiguous lane order)

__device__ __forceinline__ float phi_elu1(float x) {
    return x > 0.f ? x + 1.f : __expf(x);
}

// bijective XCD-aware swizzle (m204 form): contiguous wg chunk per XCD
__device__ __forceinline__ int xcd_swz(int orig, int nwg) {
    int q = nwg >> 3, r = nwg & 7;
    int xcd = orig & 7, off = orig >> 3;
    return (xcd < r ? xcd * (q + 1) : r * (q + 1) + (xcd - r) * q) + off;
}

// async 16B global -> LDS (DMA, no VGPR round-trip). dest must be wave-uniform base + lane*16.
__device__ __forceinline__ void gl_lds16(const bf16_t* g, bf16_t* l) {
    __builtin_amdgcn_global_load_lds(
        (const __attribute__((address_space(1))) void*)g,
        (__attribute__((address_space(3))) void*)l, 16, 0, 0);
}

// counted vmcnt wait (T4): leave N loads in flight; sched_barrier pins ordering
template<int N> __device__ __forceinline__ void waitvm() {
    asm volatile("s_waitcnt vmcnt(%0)" :: "n"(N) : "memory");
    __builtin_amdgcn_sched_barrier(0);
}

struct GemmP {
    const bf16_t* A; long lda; long aHead;
    const bf16_t* B; long ldb; long bHead;
    float* Cf; bf16_t* Cb; long ldc; long cHead; int atomicC; // 0=store 1=atomicAdd 3=per-z slab store
    int M, N, K, nSplit;
};

// C[m,n] = sum_k A[m,k]*B[n,k]; bf16 MFMA, f32 acc. K (per split) mult of 32.
// NBUF=3: LDS path, depth-2 prefetch with counted vmcnt (for deep K-loops).
// NBUF=0: register-direct path — MFMA fragments loaded straight from global
//         (use when both operands are L2-resident; no LDS, no barriers).
// NOTE: no staging bounds checks — operand buffers MUST be allocated/padded to
// tile-multiple rows (garbage rows only feed discarded C rows/cols; K-pad cols zeroed).
template<int TBM, int TBN, int NBUF = 3>
__global__ void __launch_bounds__(256)
k_mfma_nt(GemmP p)
{
    constexpr int FI = TBM / 32;
    constexpr int FJ = TBN / 32;
    constexpr int LPT = TBM / 64 + TBN / 64;   // gl_lds16 per thread per stage
    const int t  = threadIdx.x;
    const int z  = blockIdx.z;
    const int h  = z / p.nSplit;
    const int sp = z % p.nSplit;
    const int kWin = p.K / p.nSplit;
    const int k0   = sp * kWin;
    const int nwg  = gridDim.x * gridDim.y;
    const int wg   = xcd_swz(blockIdx.y * gridDim.x + blockIdx.x, nwg);
    const int m0 = (wg % gridDim.x) * TBM;
    const int n0 = (wg / gridDim.x) * TBN;
    const bf16_t* A = p.A + (long)h * p.aHead;
    const bf16_t* B = p.B + (long)h * p.bHead;

    const int lr = t >> 2;     // staging row within 64-group
    const int lc = t & 3;      // 16B chunk
    const int wid  = t >> 6;
    const int lane = t & 63;
    const int wm = (wid >> 1) * (TBM / 2);
    const int wn = (wid & 1) * (TBN / 2);
    const int fr = lane & 15;
    const int fq = lane >> 4;

    f32x4 acc[FI][FJ] = {};
    const int nSteps = kWin / BK;

    if constexpr (NBUF == 0) {
        // ---- register-direct: fragments from global (L2-resident operands) ----
        const bf16_t* aB = A + (long)(m0 + wm + fr) * p.lda + fq * 8 + k0;
        const bf16_t* bB = B + (long)(n0 + wn + fr) * p.ldb + fq * 8 + k0;
        bf16x8 a0[FI], b0[FJ], a1[FI], b1[FJ];
        auto ld = [&](bf16x8* as, bf16x8* bs, int kb) {
#pragma unroll
            for (int i = 0; i < FI; ++i)
                as[i] = *(const bf16x8*)(aB + (long)i * 16 * p.lda + kb);
#pragma unroll
            for (int j = 0; j < FJ; ++j)
                bs[j] = *(const bf16x8*)(bB + (long)j * 16 * p.ldb + kb);
        };
        auto mm = [&](bf16x8* as, bf16x8* bs) {
#pragma unroll
            for (int i = 0; i < FI; ++i)
#pragma unroll
                for (int j = 0; j < FJ; ++j)
                    acc[i][j] = __builtin_amdgcn_mfma_f32_16x16x32_bf16(as[i], bs[j], acc[i][j], 0, 0, 0);
        };
        ld(a0, b0, 0);
#pragma unroll 1
        for (int s = 0; s < nSteps; s += 2) {
            if (s + 1 < nSteps) ld(a1, b1, (s + 1) * BK);
            mm(a0, b0);
            if (s + 2 < nSteps) ld(a0, b0, (s + 2) * BK);
            if (s + 1 < nSteps) mm(a1, b1);
        }
    } else {
        // ---- LDS path: pre-swizzled global k-chunk, counted-vmcnt pipeline ----
        __shared__ bf16_t As[NBUF ? NBUF : 1][TBM * BK];
        __shared__ bf16_t Bs[NBUF ? NBUF : 1][TBN * BK];
        auto stage = [&](int buf, int kb) {
            const int gk = kb + ((lc ^ ((lr >> 1) & 3)) << 3);
#pragma unroll
            for (int it = 0; it < TBM / 64; ++it)
                gl_lds16(A + (long)(m0 + lr + it * 64) * p.lda + gk, &As[buf][it * 2048 + t * 8]);
#pragma unroll
            for (int it = 0; it < TBN / 64; ++it)
                gl_lds16(B + (long)(n0 + lr + it * 64) * p.ldb + gk, &Bs[buf][it * 2048 + t * 8]);
        };
        auto compute = [&](int cur) {
            bf16x8 af[FI], bfr[FJ];
#pragma unroll
            for (int i = 0; i < FI; ++i) {
                const int row = wm + i * 16 + fr;
                af[i] = *(const bf16x8*)(&As[cur][row * BK + ((fq ^ ((row >> 1) & 3)) << 3)]);
            }
#pragma unroll
            for (int j = 0; j < FJ; ++j) {
                const int row = wn + j * 16 + fr;
                bfr[j] = *(const bf16x8*)(&Bs[cur][row * BK + ((fq ^ ((row >> 1) & 3)) << 3)]);
            }
#pragma unroll
            for (int i = 0; i < FI; ++i)
#pragma unroll
                for (int j = 0; j < FJ; ++j)
                    acc[i][j] = __builtin_amdgcn_mfma_f32_16x16x32_bf16(af[i], bfr[j], acc[i][j], 0, 0, 0);
        };
        stage(0, k0);
        if (nSteps > 1) stage(1, k0 + BK);
        int cur = 0, pf = 2;
#pragma unroll 1
        for (int s = 0; s < nSteps; ++s) {
            if (s + 1 < nSteps) waitvm<LPT>();     // cur's loads landed; next stays in flight
            else                waitvm<0>();
            __builtin_amdgcn_s_barrier();          // all waves: cur staged, prev reads done
            __builtin_amdgcn_sched_barrier(0);
            if (s + 2 < nSteps) {                  // overwrite buf read 2 iters ago (safe past barrier)
                stage(pf, k0 + (s + 2) * BK);
                pf = (pf == 2) ? 0 : pf + 1;
            }
            compute(cur);
            cur = (cur == 2) ? 0 : cur + 1;
        }
    }

    float*  Cf = 0; bf16_t* Cb = 0;
    if (p.atomicC == 3)      Cf = p.Cf + (long)z * p.cHead;      // per-split slab, exclusive store
    else if (p.Cf)           Cf = p.Cf + (long)h * p.cHead;
    else                     Cb = p.Cb + (long)h * p.cHead;
#pragma unroll
    for (int i = 0; i < FI; ++i) {
#pragma unroll
        for (int r = 0; r < 4; ++r) {
            const int m = m0 + wm + i * 16 + fq * 4 + r;
            if (m >= p.M) continue;
#pragma unroll
            for (int j = 0; j < FJ; ++j) {
                const int n = n0 + wn + j * 16 + fr;
                if (n >= p.N) continue;
                const float v = acc[i][j][r];
                const long idx = (long)m * p.ldc + n;
                if (p.atomicC == 1)      atomicAdd(&Cf[idx], v);
                else if (Cf)             Cf[idx] = v;            // modes 0 and 3
                else                     Cb[idx] = (bf16_t)v;
            }
        }
    }
}

// KV projection, TRANSPOSED output: C[col][row] = sum_k Wkvb[col][k]*xcb[row][k].
// REGISTER-DIRECT: both operands are L2-resident (Wkvb 2.5MB, xcb 8.8MB) — MFMA
// fragments loaded straight from global; no LDS, no barriers (round-8's LDS path
// was LDS-read-pipe-bound at MfmaUtil 18%). Writes directly into Tk/Tv [2176][CHPS].
// Grid y covers ALL CHPS cols (pad cols zeroed). K-h cols (SCOL..DTOT): phi on
// f32 acc + ksum column-sum via shuffle+atomic.
__global__ void __launch_bounds__(256)
k_mfma_kv(const bf16_t* __restrict__ A, const bf16_t* __restrict__ Bsrc,
          bf16_t* __restrict__ Tk, bf16_t* __restrict__ Tv,
          float* __restrict__ ksum, int nRows)
{
    constexpr int FI = 4, FJ = 4;
    const int t = threadIdx.x;
    const int nwg = gridDim.x * gridDim.y;
    const int wg  = xcd_swz(blockIdx.y * gridDim.x + blockIdx.x, nwg);
    const int m0 = (wg % gridDim.x) * 128;   // output (weight-col) tile
    const int n0 = (wg / gridDim.x) * 128;   // source-row tile

    const int wid  = t >> 6;
    const int lane = t & 63;
    const int wm = (wid >> 1) * 64;
    const int wn = (wid & 1) * 64;
    const int fr = lane & 15;
    const int fq = lane >> 4;

    f32x4 acc[FI][FJ] = {};
    const bf16_t* aB = A    + (long)(m0 + wm + fr) * KQP + fq * 8;
    const bf16_t* bB = Bsrc + (long)(n0 + wn + fr) * KQP + fq * 8;

    bf16x8 a0[FI], b0[FJ], a1[FI], b1[FJ];
    auto ld = [&](bf16x8* as, bf16x8* bs, int kb) {
#pragma unroll
        for (int i = 0; i < FI; ++i)
            as[i] = *(const bf16x8*)(aB + (long)i * 16 * KQP + kb);
#pragma unroll
        for (int j = 0; j < FJ; ++j)
            bs[j] = *(const bf16x8*)(bB + (long)j * 16 * KQP + kb);
    };
    auto mm = [&](bf16x8* as, bf16x8* bs) {
#pragma unroll
        for (int i = 0; i < FI; ++i)
#pragma unroll
            for (int j = 0; j < FJ; ++j)
                acc[i][j] = __builtin_amdgcn_mfma_f32_16x16x32_bf16(as[i], bs[j], acc[i][j], 0, 0, 0);
    };
    constexpr int nSteps = KQP / BK;   // 9
    ld(a0, b0, 0);
#pragma unroll 1
    for (int s = 0; s < nSteps; s += 2) {
        if (s + 1 < nSteps) ld(a1, b1, (s + 1) * BK);
        mm(a0, b0);
        if (s + 2 < nSteps) ld(a0, b0, (s + 2) * BK);
        if (s + 1 < nSteps) mm(a1, b1);
    }

    const bool isKh = (m0 >= SCOL) && (m0 < DTOT);
    bf16_t* outB = (m0 < DTOT) ? (Tk + (long)m0 * CHPS)
                               : (Tv + (long)(m0 - DTOT) * CHPS);
#pragma unroll
    for (int i = 0; i < FI; ++i) {
#pragma unroll
        for (int r = 0; r < 4; ++r) {
            const int ml = wm + i * 16 + fq * 4 + r;    // local output row (weight col)
            bf16_t* row = outB + (long)ml * CHPS;
            float kacc = 0.f;
#pragma unroll
            for (int j = 0; j < FJ; ++j) {
                const int n = n0 + wn + j * 16 + fr;    // source row (output col)
                float v = 0.f;
                if (n < nRows) {
                    v = acc[i][j][r];
                    if (isKh) { v = phi_elu1(v); kacc += v; }
                }
                row[n] = (bf16_t)v;
            }
            if (isKh) {
                kacc += __shfl_xor(kacc, 1);
                kacc += __shfl_xor(kacc, 2);
                kacc += __shfl_xor(kacc, 4);
                kacc += __shfl_xor(kacc, 8);
                if (fr == 0) atomicAdd(&ksum[m0 + ml], kacc);
            }
        }
    }
}

// s-part post, transposed layout: per (source row n, head h) normalize the 17-wide
// K-s / V-s blocks in place (Tk/Tv rows h*32..h*32+16, col n), phi the K side, and
// accumulate ksum-s column sums. Loads/stores are lane-coalesced over n.
__global__ void __launch_bounds__(256)
k_post_kv_t(bf16_t* __restrict__ Tk, bf16_t* __restrict__ Tv,
            float* __restrict__ ksum, int rows)
{
    const int h = blockIdx.y;
    const int n = blockIdx.x * 256 + threadIdx.x;
    const int lane = threadIdx.x & 63;
    const bool act = n < rows;
    float kv[SD], vv[SD];
    float sk = 0.f, sv = 0.f;
#pragma unroll
    for (int j = 0; j < SD; ++j) {
        kv[j] = act ? (float)Tk[(long)(h * 32 + j) * CHPS + n] : 0.f;
        vv[j] = act ? (float)Tv[(long)(h * 32 + j) * CHPS + n] : 0.f;
        sk += kv[j] * kv[j];
        sv += vv[j] * vv[j];
    }
    const float ik = 1.f / (sqrtf(sk) + 1e-8f);
    const float iv = 1.f / (sqrtf(sv) + 1e-8f);
#pragma unroll
    for (int j = 0; j < SD; ++j) {
        float pk = act ? phi_elu1(kv[j] * ik) : 0.f;
        if (act) {
            Tk[(long)(h * 32 + j) * CHPS + n] = (bf16_t)pk;
            Tv[(long)(h * 32 + j) * CHPS + n] = (bf16_t)(vv[j] * iv);
        }
        float s = pk;
#pragma unroll
        for (int off = 32; off > 0; off >>= 1) s += __shfl_down(s, off);
        if (lane == 0) atomicAdd(&ksum[h * 32 + j], s);
    }
}

// f32 [rows][257] -> bf16 [rows][288] zero-padded, bf16x8 stores
__global__ void k_cast_pad(const float* __restrict__ in, bf16_t* __restrict__ out, long rows)
{
    long i = (long)blockIdx.x * 256 + threadIdx.x;   // 8-elem chunk id
    if (i >= rows * (KQP / 8)) return;
    long r = i / (KQP / 8); int c8 = (int)(i - r * (KQP / 8)) * 8;
    const float* ip = in + r * KIN + c8;
    bf16x8 o;
#pragma unroll
    for (int j = 0; j < 8; ++j)
        o[j] = (c8 + j < KIN) ? (bf16_t)ip[j] : (bf16_t)0.f;
    *(bf16x8*)(out + r * KQP + c8) = o;
}

// Wq/Wk/Wv [H][257][257] -> head-split padded [2176][288]
__global__ void k_prep_proj(const float* __restrict__ W, bf16_t* __restrict__ dst)
{
    long i = (long)blockIdx.x * 256 + threadIdx.x;
    if (i >= (long)DTOT * KQP) return;
    int r = (int)(i / KQP), k = (int)(i % KQP);
    float v = 0.f;
    if (r < SCOL) {
        int h = r >> 5, j = r & 31;
        if (j < SD && k < KIN) v = W[((long)h * 257 + j) * 257 + k];
    } else {
        int rr = r - SCOL;
        int h = rr / HD, j = rr % HD;
        if (k < KIN) v = W[((long)h * 257 + SD + j) * 257 + k];
    }
    dst[i] = (bf16_t)v;
}

// Ws [17][136] -> Wsb [64][256] head-split 32-padded, zero rows >= 17
__global__ void k_prep_ws(const float* __restrict__ ws, bf16_t* __restrict__ out)
{
    int o = blockIdx.x; int t = threadIdx.x;
    int h = t >> 5, j = t & 31;
    float v = 0.f;
    if (o < SD && j < SD) v = ws[o * (H * SD) + h * SD + j];
    out[o * 256 + t] = (bf16_t)v;
}

// Wh [240][1920] -> Whb [256][2048] head-split 256-padded, zero rows >= 240
__global__ void k_prep_wh(const float* __restrict__ wh, bf16_t* __restrict__ out)
{
    long i = (long)blockIdx.x * 256 + threadIdx.x;
    if (i >= 256L * 2048) return;
    int o = (int)(i / 2048), c = (int)(i % 2048);
    int h = c >> 8, j = c & 255;
    float v = 0.f;
    if (o < 240 && j < HD) v = wh[(long)o * 1920 + h * HD + j];
    out[i] = (bf16_t)v;
}

// post for Q: phi + s-norm, compute den vs ksum, scale by 1/(den+eps) IN PLACE.
// h-part vectorized: 240 = 30 lanes x bf16x8.
__global__ void __launch_bounds__(256)
k_post_q(bf16_t* __restrict__ Yq, const float* __restrict__ ksum, int rows)
{
    const int wid  = blockIdx.x * 4 + (threadIdx.x >> 6);
    const int lane = threadIdx.x & 63;
    const int n = wid >> 3, h = wid & 7;
    if (n >= rows) return;
    bf16_t* row = Yq + (long)n * DTOT;
    float qv = (lane < SD) ? (float)row[h * 32 + lane] : 0.f;
    float sq = qv * qv;
#pragma unroll
    for (int off = 32; off > 0; off >>= 1) sq += __shfl_down(sq, off);
    sq = __shfl(sq, 0);
    const float iq = 1.f / (sqrtf(sq) + 1e-8f);
    float pvs = (lane < SD) ? phi_elu1(qv * iq) : 0.f;
    float ds = (lane < SD) ? pvs * ksum[h * 32 + lane] : 0.f;
    float ph[8];
    float dh = 0.f;
    if (lane < 30) {
        bf16x8 hv8 = *(const bf16x8*)(row + SCOL + h * HD + lane * 8);
        const float* kp = ksum + SCOL + h * HD + lane * 8;
#pragma unroll
        for (int i = 0; i < 8; ++i) {
            ph[i] = phi_elu1((float)hv8[i]);
            dh += ph[i] * kp[i];
        }
    }
#pragma unroll
    for (int off = 32; off > 0; off >>= 1) {
        ds += __shfl_down(ds, off);
        dh += __shfl_down(dh, off);
    }
    ds = __shfl(ds, 0); dh = __shfl(dh, 0);
    const float ss = 1.f / (ds + 1e-6f);
    const float sh = 1.f / (dh + 1e-8f);
    if (lane < 32)
        row[h * 32 + lane] = (bf16_t)((lane < SD) ? pvs * ss : 0.f);
    if (lane < 30) {
        bf16x8 o8;
#pragma unroll
        for (int i = 0; i < 8; ++i) o8[i] = (bf16_t)(ph[i] * sh);
        *(bf16x8*)(row + SCOL + h * HD + lane * 8) = o8;
    }
}

// f32 -> bf16
__global__ void k_castf(const float* __restrict__ in, bf16_t* __restrict__ out, long n)
{
    long i = (long)blockIdx.x * 256 + threadIdx.x;
    if (i < n) out[i] = (bf16_t)in[i];
}

// final epilogue: sums the OSPLIT K-split slabs of opre, then normalizes
__global__ void __launch_bounds__(256)
k_finalize(const float* __restrict__ pre, float* __restrict__ outp, int rows)
{
    int n    = blockIdx.x * 4 + (threadIdx.x >> 6);
    int lane = threadIdx.x & 63;
    if (n >= rows) return;
    const float* rp = pre + (long)n * 257;
    float* op = outp + (long)n * 257;
    float sv = 0.f;
    if (lane < SD) {
#pragma unroll
        for (int s = 0; s < OSPLIT; ++s) sv += rp[s * OSLAB + lane];
    }
    float ssq = sv * sv;
    float hv[4];
    float hsq = 0.f;
#pragma unroll
    for (int i = 0; i < 4; ++i) {
        int o = lane + 64 * i;
        float v = 0.f;
        if (o < HD) {
#pragma unroll
            for (int s = 0; s < OSPLIT; ++s) v += rp[s * OSLAB + SD + o];
        }
        hv[i] = v;
        hsq += v * v;
    }
#pragma unroll
    for (int off = 32; off > 0; off >>= 1) {
        ssq += __shfl_down(ssq, off);
        hsq += __shfl_down(hsq, off);
    }
    ssq = __shfl(ssq, 0); hsq = __shfl(hsq, 0);
    float an_raw = sqrtf(ssq);
    float bn_raw = sqrtf(hsq);
    float an = an_raw + 1e-8f;
    float bn = bn_raw + 1e-8f;
    bool ma = an > 1e6f;
    bool mb = bn > 1e6f;
    float an_c = fminf(an, 1e6f);
    float bn_c = fminf(bn, 1e6f);
    float na = ma ? (an_raw / an_c) : an_raw;
    na = fmaxf(na, 1e-12f);
    float inv_s = (ma ? (1.f / an_c) : 1.f) / na;
    float bt = sqrtf(bn_c * bn_c + 1.0f);
    float nb = fmaxf(bn_raw / bn_c, 1e-12f);
    float scale_b = 1e6f / (bn_c * nb);
    if (lane < SD) op[lane] = bt * (sv * inv_s);
#pragma unroll
    for (int i = 0; i < 4; ++i) {
        int o = lane + 64 * i;
        if (o < HD) op[SD + o] = mb ? hv[i] * scale_b : hv[i];
    }
}

static inline long alup(long b) { return (b + 255) & ~255L; }

extern "C" void kernel_launch(void* const* d_in, const int* in_sizes, int n_in,
                              void* d_out, int out_size, void* d_ws, size_t ws_size,
                              hipStream_t stream)
{
    const float* query  = (const float*)d_in[0];
    const float* source = (const float*)d_in[1];
    const float* Wq     = (const float*)d_in[2];
    const float* Wk     = (const float*)d_in[3];
    const float* Wv     = (const float*)d_in[4];
    const float* Ws     = (const float*)d_in[5];
    const float* Wh     = (const float*)d_in[6];
    float* out = (float*)d_out;

    // ---- workspace (~152 MB; proven ws >= ~205 MB). All GEMM operands padded to
    // tile-multiple rows because register-direct loads have no bounds checks. ----
    char* p = (char*)d_ws;
    auto alloc = [&](long b) { char* r = p; p += alup(b); return r; };
    bf16_t* Wkvb = (bf16_t*)alloc(2L * DTOT * KQP * 2);       // [4352][288]
    bf16_t* Wqb  = (bf16_t*)alloc((long)DTOT * KQP * 2);      // [2176][288]
    bf16_t* Wsb  = (bf16_t*)alloc(64L * 256 * 2);             // [64][256] zero-padded
    bf16_t* Whb  = (bf16_t*)alloc(256L * 2048 * 2);           // [256][2048] zero-padded
    bf16_t* Gfull= (bf16_t*)alloc(384L * DTOT * 2);           // [384][2176] zeroed (192-tile staging)
    float*  ktvF = (float*) alloc((8L * HD * 256 + 8L * 32 * 32) * 4);
    float*  ksum = (float*) alloc((long)DTOT * 4);            // contiguous after ktvF
    bf16_t* ktvB = (bf16_t*)alloc((8L * HD * 256 + 8L * 32 * 32) * 2);
    bf16_t* xcb  = (bf16_t*)alloc((long)XROWS * KQP * 2);     // [15360][288]
    // union: source {Tk,Tv(+16 slack rows)} / query {Yq(15104 rows), opre slabs}
    long tkBytes = (long)DTOT * CHPS * 2;
    char* ub = alloc(2 * tkBytes + 16L * CHPS * 2);
    bf16_t* Tk  = (bf16_t*)ub;
    bf16_t* Tv  = Tk + (long)DTOT * CHPS;
    bf16_t* Yq  = Tk;                                         // [15104][2176]
    float*  opre= (float*)(Yq + (long)YQROWS * DTOT);         // OSPLIT slabs [15104][257] f32

    float*  ktvHf = ktvF;
    float*  ktvSf = ktvF + 8L * HD * 256;
    bf16_t* ktvHb = ktvB;
    bf16_t* ktvSb = ktvB + 8L * HD * 256;

    (void)hipMemsetAsync(ktvF, 0, (char*)(ksum + DTOT) - (char*)ktvF, stream);
    (void)hipMemsetAsync(Gfull, 0, 384L * DTOT * 2, stream);

    // ---- weight prep ----
    const unsigned gw = (unsigned)(((long)DTOT * KQP + 255) / 256);
    k_prep_proj<<<gw, 256, 0, stream>>>(Wk, Wkvb);
    k_prep_proj<<<gw, 256, 0, stream>>>(Wv, Wkvb + (long)DTOT * KQP);
    k_prep_proj<<<gw, 256, 0, stream>>>(Wq, Wqb);
    k_prep_ws<<<64, 256, 0, stream>>>(Ws, Wsb);
    k_prep_wh<<<(unsigned)((256L * 2048 + 255) / 256), 256, 0, stream>>>(Wh, Whb);

    GemmP g;

    // ---------------- source phase (2 chunks of 15000) ----------------
    for (int c = 0; c < NCS; ++c) {
        const float* src = source + (long)c * CHS * KIN;
        k_cast_pad<<<(unsigned)(((long)CHS * (KQP / 8) + 255) / 256), 256, 0, stream>>>(src, xcb, CHS);
        // Tk/Tv = (xcb @ Wkvb^T)^T written directly, phi+ksum fused for K-h.
        // register-direct; grid y covers all CHPS cols (pad cols zeroed here).
        k_mfma_kv<<<dim3((2 * DTOT) / 128, CHPS / 128, 1), 256, 0, stream>>>(
            Wkvb, xcb, Tk, Tv, ksum, CHS);
        k_post_kv_t<<<dim3((CHS + 255) / 256, H), 256, 0, stream>>>(Tk, Tv, ksum, CHS);
        // ktvH_h[k'][v] += sum_n Tk_h[k'][n]*Tv_h[v][n]  (K = 15360, 30 steps/split)
        g = { Tk + (long)SCOL * CHPS, CHPS, (long)HD * CHPS,
              Tv + (long)SCOL * CHPS, CHPS, (long)HD * CHPS,
              ktvHf, 0, 256, (long)HD * 256, 1,  HD, HD, CHPS, KSPLIT };
        k_mfma_nt<128, 128><<<dim3(2, 2, H * KSPLIT), 256, 0, stream>>>(g);
        g = { Tk, CHPS, 32L * CHPS,  Tv, CHPS, 32L * CHPS,
              ktvSf, 0, 32, 32L * 32, 1,  32, 32, CHPS, KSPLIT };
        k_mfma_nt<64, 64><<<dim3(1, 1, H * KSPLIT), 256, 0, stream>>>(g);
    }
    k_castf<<<(unsigned)((8L * (HD * 256 + 32 * 32) + 255) / 256), 256, 0, stream>>>(
        ktvF, ktvB, 8L * (HD * 256 + 32 * 32));

    // ---- fold ktv into output weights: Gfull[o][k] ----
    g = { Wsb, 256, 32,  ktvSb, 32, 32L * 32,  0, Gfull, DTOT, 32, 0,
          SD, 32, 32, 1 };
    k_mfma_nt<64, 64><<<dim3(1, 1, H), 256, 0, stream>>>(g);
    g = { Whb, 2048, 256,  ktvHb, 256, (long)HD * 256,
          0, Gfull + 17L * DTOT + SCOL, DTOT, HD, 0,
          HD, HD, 256, 1 };
    k_mfma_nt<64, 64><<<dim3(4, 4, H), 256, 0, stream>>>(g);

    // ---------------- query phase (2 chunks of 15000) ----------------
    for (int c = 0; c < NCQ; ++c) {
        const float* qsrc = query + (long)c * CHQ * KIN;
        float* orow = out + (long)c * CHQ * 257;
        k_cast_pad<<<(unsigned)(((long)CHQ * (KQP / 8) + 255) / 256), 256, 0, stream>>>(qsrc, xcb, CHQ);
        // Yq = xcb @ Wqb^T : register-direct (both operands L2-resident)
        g = { xcb, KQP, 0,  Wqb, KQP, 0,  0, Yq, DTOT, 0, 0,
              CHQ, DTOT, KQP, 1 };
        k_mfma_nt<128, 128, 0><<<dim3((CHQ + 127) / 128, DTOT / 128, 1), 256, 0, stream>>>(g);
        k_post_q<<<(CHQ * H) / 4, 256, 0, stream>>>(Yq, ksum, CHQ);
        // opre slabs = Yq_scaled @ Gfull^T, K split into OSPLIT windows (exclusive slab stores)
        g = { Yq, DTOT, 0,  Gfull, DTOT, 0,  opre, 0, 257, OSLAB, 3,
              CHQ, 257, DTOT, OSPLIT };
        k_mfma_nt<64, 192><<<dim3((CHQ + 63) / 64, 2, OSPLIT), 256, 0, stream>>>(g);
        k_finalize<<<(CHQ + 3) / 4, 256, 0, stream>>>(opre, orow, CHQ);
    }
}

// Round 12
// 947.824 us; speedup vs baseline: 1.2071x; 1.0851x over previous
//
#include <hip/hip_runtime.h>
#include <math.h>

typedef __bf16 bf16_t;
typedef __bf16 bf16x8 __attribute__((ext_vector_type(8)));
typedef float f32x4 __attribute__((ext_vector_type(4)));

#define H    8
#define SD   17
#define HD   240
#define KIN  257
#define KQP  288      // padded K for projections
#define SCOL 256      // s-block width (8 x 32)
#define DTOT 2176     // 256 + 1920
#define NTOT 30000
#define CHS  15000    // source chunk
#define NCS  2
#define CHPS 15360    // CHS padded to 256 and to KSPLIT*32 (=512 mult)
#define CHQ  15000    // query chunk
#define NCQ  2
#define YQROWS 15104  // Yq rows incl. staging pad
#define XROWS 15360   // xcb rows incl. staging pad (kv grid covers CHPS)
#define KSPLIT 16
#define OSPLIT 4      // opre K-split
#define OSLAB (15104L * 257)

#define BK   32       // LDS row stride = BK halves (NO pad: global_load_lds needs contiguous lane order)

__device__ __forceinline__ float phi_elu1(float x) {
    return x > 0.f ? x + 1.f : __expf(x);
}

// bijective XCD-aware swizzle (m204 form): contiguous wg chunk per XCD
__device__ __forceinline__ int xcd_swz(int orig, int nwg) {
    int q = nwg >> 3, r = nwg & 7;
    int xcd = orig & 7, off = orig >> 3;
    return (xcd < r ? xcd * (q + 1) : r * (q + 1) + (xcd - r) * q) + off;
}

// async 16B global -> LDS (DMA, no VGPR round-trip). dest must be wave-uniform base + lane*16.
__device__ __forceinline__ void gl_lds16(const bf16_t* g, bf16_t* l) {
    __builtin_amdgcn_global_load_lds(
        (const __attribute__((address_space(1))) void*)g,
        (__attribute__((address_space(3))) void*)l, 16, 0, 0);
}

// counted vmcnt wait (T4): leave N loads in flight; sched_barrier pins ordering
template<int N> __device__ __forceinline__ void waitvm() {
    asm volatile("s_waitcnt vmcnt(%0)" :: "n"(N) : "memory");
    __builtin_amdgcn_sched_barrier(0);
}

struct GemmP {
    const bf16_t* A; long lda; long aHead;
    const bf16_t* B; long ldb; long bHead;
    float* Cf; bf16_t* Cb; long ldc; long cHead; int atomicC; // 0=store 1=atomicAdd 3=per-z slab store
    int M, N, K, nSplit;
};

// C[m,n] = sum_k A[m,k]*B[n,k]; bf16 MFMA, f32 acc. K (per split) mult of 32.
// 3-buffer depth-2 pipeline, counted vmcnt (never drains to 0 mid-loop),
// one raw s_barrier per K-step, XOR chunk-swizzle on LDS (both sides).
// NOTE: no staging bounds checks — operand buffers MUST be allocated/padded to
// tile-multiple rows (garbage rows only feed discarded C rows/cols; K-pad cols zeroed).
template<int TBM, int TBN>
__global__ void __launch_bounds__(256)
k_mfma_nt(GemmP p)
{
    constexpr int FI = TBM / 32;
    constexpr int FJ = TBN / 32;
    constexpr int LPT = TBM / 64 + TBN / 64;   // gl_lds16 per thread per stage
    __shared__ bf16_t As[3][TBM * BK];
    __shared__ bf16_t Bs[3][TBN * BK];
    const int t  = threadIdx.x;
    const int z  = blockIdx.z;
    const int h  = z / p.nSplit;
    const int sp = z % p.nSplit;
    const int kWin = p.K / p.nSplit;
    const int k0   = sp * kWin;
    const int nwg  = gridDim.x * gridDim.y;
    const int wg   = xcd_swz(blockIdx.y * gridDim.x + blockIdx.x, nwg);
    const int m0 = (wg % gridDim.x) * TBM;
    const int n0 = (wg / gridDim.x) * TBN;
    const bf16_t* A = p.A + (long)h * p.aHead;
    const bf16_t* B = p.B + (long)h * p.bHead;

    const int lr = t >> 2;     // staging row within 64-group
    const int lc = t & 3;      // 16B chunk
    const int wid  = t >> 6;
    const int lane = t & 63;
    const int wm = (wid >> 1) * (TBM / 2);
    const int wn = (wid & 1) * (TBN / 2);
    const int fr = lane & 15;
    const int fq = lane >> 4;

    f32x4 acc[FI][FJ] = {};

    // pre-swizzled global k-chunk: LDS slot (row, c) holds global chunk c ^ ((row>>1)&3)
    auto stage = [&](int buf, int kb) {
        const int gk = kb + ((lc ^ ((lr >> 1) & 3)) << 3);
#pragma unroll
        for (int it = 0; it < TBM / 64; ++it)
            gl_lds16(A + (long)(m0 + lr + it * 64) * p.lda + gk, &As[buf][it * 2048 + t * 8]);
#pragma unroll
        for (int it = 0; it < TBN / 64; ++it)
            gl_lds16(B + (long)(n0 + lr + it * 64) * p.ldb + gk, &Bs[buf][it * 2048 + t * 8]);
    };

    const int nSteps = kWin / BK;
    stage(0, k0);
    if (nSteps > 1) stage(1, k0 + BK);
    int cur = 0, pf = 2;
#pragma unroll 1
    for (int s = 0; s < nSteps; ++s) {
        if (s + 1 < nSteps) waitvm<LPT>();     // cur's loads landed; next stays in flight
        else                waitvm<0>();
        __builtin_amdgcn_s_barrier();          // all waves: cur staged, prev reads done
        __builtin_amdgcn_sched_barrier(0);
        if (s + 2 < nSteps) {                  // overwrite buf read 2 iters ago (safe past barrier)
            stage(pf, k0 + (s + 2) * BK);
            pf = (pf == 2) ? 0 : pf + 1;
        }
        bf16x8 af[FI], bfr[FJ];
#pragma unroll
        for (int i = 0; i < FI; ++i) {
            const int row = wm + i * 16 + fr;
            af[i] = *(const bf16x8*)(&As[cur][row * BK + ((fq ^ ((row >> 1) & 3)) << 3)]);
        }
#pragma unroll
        for (int j = 0; j < FJ; ++j) {
            const int row = wn + j * 16 + fr;
            bfr[j] = *(const bf16x8*)(&Bs[cur][row * BK + ((fq ^ ((row >> 1) & 3)) << 3)]);
        }
#pragma unroll
        for (int i = 0; i < FI; ++i)
#pragma unroll
            for (int j = 0; j < FJ; ++j)
                acc[i][j] = __builtin_amdgcn_mfma_f32_16x16x32_bf16(af[i], bfr[j], acc[i][j], 0, 0, 0);
        cur = (cur == 2) ? 0 : cur + 1;
    }

    float*  Cf = 0; bf16_t* Cb = 0;
    if (p.atomicC == 3)      Cf = p.Cf + (long)z * p.cHead;      // per-split slab, exclusive store
    else if (p.Cf)           Cf = p.Cf + (long)h * p.cHead;
    else                     Cb = p.Cb + (long)h * p.cHead;
#pragma unroll
    for (int i = 0; i < FI; ++i) {
#pragma unroll
        for (int r = 0; r < 4; ++r) {
            const int m = m0 + wm + i * 16 + fq * 4 + r;
            if (m >= p.M) continue;
#pragma unroll
            for (int j = 0; j < FJ; ++j) {
                const int n = n0 + wn + j * 16 + fr;
                if (n >= p.N) continue;
                const float v = acc[i][j][r];
                const long idx = (long)m * p.ldc + n;
                if (p.atomicC == 1)      atomicAdd(&Cf[idx], v);
                else if (Cf)             Cf[idx] = v;            // modes 0 and 3
                else                     Cb[idx] = (bf16_t)v;
            }
        }
    }
}

// KV projection, TRANSPOSED output: C[col][row] = sum_k Wkvb[col][k]*xcb[row][k].
// Writes directly into Tk/Tv [2176][CHPS] (no Ykv, no transpose kernel).
// Same 3-buffer counted-vmcnt pipeline + LDS swizzle as k_mfma_nt.
// Grid y covers ALL CHPS cols: cols >= nRows written as 0 (no zero_tail needed).
// K-h cols (SCOL..DTOT): phi applied on f32 acc + ksum column-sum via shuffle+atomic.
__global__ void __launch_bounds__(256)
k_mfma_kv(const bf16_t* __restrict__ A, const bf16_t* __restrict__ Bsrc,
          bf16_t* __restrict__ Tk, bf16_t* __restrict__ Tv,
          float* __restrict__ ksum, int nRows)
{
    constexpr int FI = 4, FJ = 4;
    constexpr int LPT = 4;
    __shared__ bf16_t As[3][128 * BK];
    __shared__ bf16_t Bs[3][128 * BK];
    const int t = threadIdx.x;
    const int nwg = gridDim.x * gridDim.y;
    const int wg  = xcd_swz(blockIdx.y * gridDim.x + blockIdx.x, nwg);
    const int m0 = (wg % gridDim.x) * 128;   // output (weight-col) tile
    const int n0 = (wg / gridDim.x) * 128;   // source-row tile

    const int lr = t >> 2;
    const int lc = t & 3;
    const int wid  = t >> 6;
    const int lane = t & 63;
    const int wm = (wid >> 1) * 64;
    const int wn = (wid & 1) * 64;
    const int fr = lane & 15;
    const int fq = lane >> 4;

    f32x4 acc[FI][FJ] = {};

    auto stage = [&](int buf, int kb) {
        const int gk = kb + ((lc ^ ((lr >> 1) & 3)) << 3);
        gl_lds16(A    + (long)(m0 + lr)      * KQP + gk, &As[buf][t * 8]);
        gl_lds16(A    + (long)(m0 + lr + 64) * KQP + gk, &As[buf][2048 + t * 8]);
        gl_lds16(Bsrc + (long)(n0 + lr)      * KQP + gk, &Bs[buf][t * 8]);
        gl_lds16(Bsrc + (long)(n0 + lr + 64) * KQP + gk, &Bs[buf][2048 + t * 8]);
    };

    constexpr int nSteps = KQP / BK;   // 9
    stage(0, 0);
    stage(1, BK);
    int cur = 0, pf = 2;
#pragma unroll 1
    for (int s = 0; s < nSteps; ++s) {
        if (s + 1 < nSteps) waitvm<LPT>();
        else                waitvm<0>();
        __builtin_amdgcn_s_barrier();
        __builtin_amdgcn_sched_barrier(0);
        if (s + 2 < nSteps) {
            stage(pf, (s + 2) * BK);
            pf = (pf == 2) ? 0 : pf + 1;
        }
        bf16x8 af[FI], bfr[FJ];
#pragma unroll
        for (int i = 0; i < FI; ++i) {
            const int row = wm + i * 16 + fr;
            af[i] = *(const bf16x8*)(&As[cur][row * BK + ((fq ^ ((row >> 1) & 3)) << 3)]);
        }
#pragma unroll
        for (int j = 0; j < FJ; ++j) {
            const int row = wn + j * 16 + fr;
            bfr[j] = *(const bf16x8*)(&Bs[cur][row * BK + ((fq ^ ((row >> 1) & 3)) << 3)]);
        }
#pragma unroll
        for (int i = 0; i < FI; ++i)
#pragma unroll
            for (int j = 0; j < FJ; ++j)
                acc[i][j] = __builtin_amdgcn_mfma_f32_16x16x32_bf16(af[i], bfr[j], acc[i][j], 0, 0, 0);
        cur = (cur == 2) ? 0 : cur + 1;
    }

    const bool isKh = (m0 >= SCOL) && (m0 < DTOT);
    bf16_t* outB = (m0 < DTOT) ? (Tk + (long)m0 * CHPS)
                               : (Tv + (long)(m0 - DTOT) * CHPS);
#pragma unroll
    for (int i = 0; i < FI; ++i) {
#pragma unroll
        for (int r = 0; r < 4; ++r) {
            const int ml = wm + i * 16 + fq * 4 + r;    // local output row (weight col)
            bf16_t* row = outB + (long)ml * CHPS;
            float kacc = 0.f;
#pragma unroll
            for (int j = 0; j < FJ; ++j) {
                const int n = n0 + wn + j * 16 + fr;    // source row (output col)
                float v = 0.f;
                if (n < nRows) {
                    v = acc[i][j][r];
                    if (isKh) { v = phi_elu1(v); kacc += v; }
                }
                row[n] = (bf16_t)v;
            }
            if (isKh) {
                kacc += __shfl_xor(kacc, 1);
                kacc += __shfl_xor(kacc, 2);
                kacc += __shfl_xor(kacc, 4);
                kacc += __shfl_xor(kacc, 8);
                if (fr == 0) atomicAdd(&ksum[m0 + ml], kacc);
            }
        }
    }
}

// s-part post, transposed layout: per (source row n, head h) normalize the 17-wide
// K-s / V-s blocks in place (Tk/Tv rows h*32..h*32+16, col n), phi the K side, and
// accumulate ksum-s column sums. Loads/stores are lane-coalesced over n.
__global__ void __launch_bounds__(256)
k_post_kv_t(bf16_t* __restrict__ Tk, bf16_t* __restrict__ Tv,
            float* __restrict__ ksum, int rows)
{
    const int h = blockIdx.y;
    const int n = blockIdx.x * 256 + threadIdx.x;
    const int lane = threadIdx.x & 63;
    const bool act = n < rows;
    float kv[SD], vv[SD];
    float sk = 0.f, sv = 0.f;
#pragma unroll
    for (int j = 0; j < SD; ++j) {
        kv[j] = act ? (float)Tk[(long)(h * 32 + j) * CHPS + n] : 0.f;
        vv[j] = act ? (float)Tv[(long)(h * 32 + j) * CHPS + n] : 0.f;
        sk += kv[j] * kv[j];
        sv += vv[j] * vv[j];
    }
    const float ik = 1.f / (sqrtf(sk) + 1e-8f);
    const float iv = 1.f / (sqrtf(sv) + 1e-8f);
#pragma unroll
    for (int j = 0; j < SD; ++j) {
        float pk = act ? phi_elu1(kv[j] * ik) : 0.f;
        if (act) {
            Tk[(long)(h * 32 + j) * CHPS + n] = (bf16_t)pk;
            Tv[(long)(h * 32 + j) * CHPS + n] = (bf16_t)(vv[j] * iv);
        }
        float s = pk;
#pragma unroll
        for (int off = 32; off > 0; off >>= 1) s += __shfl_down(s, off);
        if (lane == 0) atomicAdd(&ksum[h * 32 + j], s);
    }
}

// f32 [rows][257] -> bf16 [rows][288] zero-padded, bf16x8 stores
__global__ void k_cast_pad(const float* __restrict__ in, bf16_t* __restrict__ out, long rows)
{
    long i = (long)blockIdx.x * 256 + threadIdx.x;   // 8-elem chunk id
    if (i >= rows * (KQP / 8)) return;
    long r = i / (KQP / 8); int c8 = (int)(i - r * (KQP / 8)) * 8;
    const float* ip = in + r * KIN + c8;
    bf16x8 o;
#pragma unroll
    for (int j = 0; j < 8; ++j)
        o[j] = (c8 + j < KIN) ? (bf16_t)ip[j] : (bf16_t)0.f;
    *(bf16x8*)(out + r * KQP + c8) = o;
}

// Wq/Wk/Wv [H][257][257] -> head-split padded [2176][288]
__global__ void k_prep_proj(const float* __restrict__ W, bf16_t* __restrict__ dst)
{
    long i = (long)blockIdx.x * 256 + threadIdx.x;
    if (i >= (long)DTOT * KQP) return;
    int r = (int)(i / KQP), k = (int)(i % KQP);
    float v = 0.f;
    if (r < SCOL) {
        int h = r >> 5, j = r & 31;
        if (j < SD && k < KIN) v = W[((long)h * 257 + j) * 257 + k];
    } else {
        int rr = r - SCOL;
        int h = rr / HD, j = rr % HD;
        if (k < KIN) v = W[((long)h * 257 + SD + j) * 257 + k];
    }
    dst[i] = (bf16_t)v;
}

// Ws [17][136] -> Wsb [64][256] head-split 32-padded, zero rows >= 17
__global__ void k_prep_ws(const float* __restrict__ ws, bf16_t* __restrict__ out)
{
    int o = blockIdx.x; int t = threadIdx.x;
    int h = t >> 5, j = t & 31;
    float v = 0.f;
    if (o < SD && j < SD) v = ws[o * (H * SD) + h * SD + j];
    out[o * 256 + t] = (bf16_t)v;
}

// Wh [240][1920] -> Whb [256][2048] head-split 256-padded, zero rows >= 240
__global__ void k_prep_wh(const float* __restrict__ wh, bf16_t* __restrict__ out)
{
    long i = (long)blockIdx.x * 256 + threadIdx.x;
    if (i >= 256L * 2048) return;
    int o = (int)(i / 2048), c = (int)(i % 2048);
    int h = c >> 8, j = c & 255;
    float v = 0.f;
    if (o < 240 && j < HD) v = wh[(long)o * 1920 + h * HD + j];
    out[i] = (bf16_t)v;
}

// post for Q: phi + s-norm, compute den vs ksum, scale by 1/(den+eps) IN PLACE.
// h-part vectorized: 240 = 30 lanes x bf16x8.
__global__ void __launch_bounds__(256)
k_post_q(bf16_t* __restrict__ Yq, const float* __restrict__ ksum, int rows)
{
    const int wid  = blockIdx.x * 4 + (threadIdx.x >> 6);
    const int lane = threadIdx.x & 63;
    const int n = wid >> 3, h = wid & 7;
    if (n >= rows) return;
    bf16_t* row = Yq + (long)n * DTOT;
    float qv = (lane < SD) ? (float)row[h * 32 + lane] : 0.f;
    float sq = qv * qv;
#pragma unroll
    for (int off = 32; off > 0; off >>= 1) sq += __shfl_down(sq, off);
    sq = __shfl(sq, 0);
    const float iq = 1.f / (sqrtf(sq) + 1e-8f);
    float pvs = (lane < SD) ? phi_elu1(qv * iq) : 0.f;
    float ds = (lane < SD) ? pvs * ksum[h * 32 + lane] : 0.f;
    float ph[8];
    float dh = 0.f;
    if (lane < 30) {
        bf16x8 hv8 = *(const bf16x8*)(row + SCOL + h * HD + lane * 8);
        const float* kp = ksum + SCOL + h * HD + lane * 8;
#pragma unroll
        for (int i = 0; i < 8; ++i) {
            ph[i] = phi_elu1((float)hv8[i]);
            dh += ph[i] * kp[i];
        }
    }
#pragma unroll
    for (int off = 32; off > 0; off >>= 1) {
        ds += __shfl_down(ds, off);
        dh += __shfl_down(dh, off);
    }
    ds = __shfl(ds, 0); dh = __shfl(dh, 0);
    const float ss = 1.f / (ds + 1e-6f);
    const float sh = 1.f / (dh + 1e-8f);
    if (lane < 32)
        row[h * 32 + lane] = (bf16_t)((lane < SD) ? pvs * ss : 0.f);
    if (lane < 30) {
        bf16x8 o8;
#pragma unroll
        for (int i = 0; i < 8; ++i) o8[i] = (bf16_t)(ph[i] * sh);
        *(bf16x8*)(row + SCOL + h * HD + lane * 8) = o8;
    }
}

// f32 -> bf16
__global__ void k_castf(const float* __restrict__ in, bf16_t* __restrict__ out, long n)
{
    long i = (long)blockIdx.x * 256 + threadIdx.x;
    if (i < n) out[i] = (bf16_t)in[i];
}

// final epilogue: sums the OSPLIT K-split slabs of opre, then normalizes
__global__ void __launch_bounds__(256)
k_finalize(const float* __restrict__ pre, float* __restrict__ outp, int rows)
{
    int n    = blockIdx.x * 4 + (threadIdx.x >> 6);
    int lane = threadIdx.x & 63;
    if (n >= rows) return;
    const float* rp = pre + (long)n * 257;
    float* op = outp + (long)n * 257;
    float sv = 0.f;
    if (lane < SD) {
#pragma unroll
        for (int s = 0; s < OSPLIT; ++s) sv += rp[s * OSLAB + lane];
    }
    float ssq = sv * sv;
    float hv[4];
    float hsq = 0.f;
#pragma unroll
    for (int i = 0; i < 4; ++i) {
        int o = lane + 64 * i;
        float v = 0.f;
        if (o < HD) {
#pragma unroll
            for (int s = 0; s < OSPLIT; ++s) v += rp[s * OSLAB + SD + o];
        }
        hv[i] = v;
        hsq += v * v;
    }
#pragma unroll
    for (int off = 32; off > 0; off >>= 1) {
        ssq += __shfl_down(ssq, off);
        hsq += __shfl_down(hsq, off);
    }
    ssq = __shfl(ssq, 0); hsq = __shfl(hsq, 0);
    float an_raw = sqrtf(ssq);
    float bn_raw = sqrtf(hsq);
    float an = an_raw + 1e-8f;
    float bn = bn_raw + 1e-8f;
    bool ma = an > 1e6f;
    bool mb = bn > 1e6f;
    float an_c = fminf(an, 1e6f);
    float bn_c = fminf(bn, 1e6f);
    float na = ma ? (an_raw / an_c) : an_raw;
    na = fmaxf(na, 1e-12f);
    float inv_s = (ma ? (1.f / an_c) : 1.f) / na;
    float bt = sqrtf(bn_c * bn_c + 1.0f);
    float nb = fmaxf(bn_raw / bn_c, 1e-12f);
    float scale_b = 1e6f / (bn_c * nb);
    if (lane < SD) op[lane] = bt * (sv * inv_s);
#pragma unroll
    for (int i = 0; i < 4; ++i) {
        int o = lane + 64 * i;
        if (o < HD) op[SD + o] = mb ? hv[i] * scale_b : hv[i];
    }
}

static inline long alup(long b) { return (b + 255) & ~255L; }

extern "C" void kernel_launch(void* const* d_in, const int* in_sizes, int n_in,
                              void* d_out, int out_size, void* d_ws, size_t ws_size,
                              hipStream_t stream)
{
    const float* query  = (const float*)d_in[0];
    const float* source = (const float*)d_in[1];
    const float* Wq     = (const float*)d_in[2];
    const float* Wk     = (const float*)d_in[3];
    const float* Wv     = (const float*)d_in[4];
    const float* Ws     = (const float*)d_in[5];
    const float* Wh     = (const float*)d_in[6];
    float* out = (float*)d_out;

    // ---- workspace (~152 MB; proven ws >= ~205 MB). All GEMM operands padded to
    // tile-multiple rows because async staging has no bounds checks. ----
    char* p = (char*)d_ws;
    auto alloc = [&](long b) { char* r = p; p += alup(b); return r; };
    bf16_t* Wkvb = (bf16_t*)alloc(2L * DTOT * KQP * 2);       // [4352][288]
    bf16_t* Wqb  = (bf16_t*)alloc((long)DTOT * KQP * 2);      // [2176][288]
    bf16_t* Wsb  = (bf16_t*)alloc(64L * 256 * 2);             // [64][256] zero-padded
    bf16_t* Whb  = (bf16_t*)alloc(256L * 2048 * 2);           // [256][2048] zero-padded
    bf16_t* Gfull= (bf16_t*)alloc(384L * DTOT * 2);           // [384][2176] zeroed (192-tile staging)
    float*  ktvF = (float*) alloc((8L * HD * 256 + 8L * 32 * 32) * 4);
    float*  ksum = (float*) alloc((long)DTOT * 4);            // contiguous after ktvF
    bf16_t* ktvB = (bf16_t*)alloc((8L * HD * 256 + 8L * 32 * 32) * 2);
    bf16_t* xcb  = (bf16_t*)alloc((long)XROWS * KQP * 2);     // [15360][288]
    // union: source {Tk,Tv(+16 slack rows)} / query {Yq(15104 rows), opre slabs}
    long tkBytes = (long)DTOT * CHPS * 2;
    char* ub = alloc(2 * tkBytes + 16L * CHPS * 2);
    bf16_t* Tk  = (bf16_t*)ub;
    bf16_t* Tv  = Tk + (long)DTOT * CHPS;
    bf16_t* Yq  = Tk;                                         // [15104][2176]
    float*  opre= (float*)(Yq + (long)YQROWS * DTOT);         // OSPLIT slabs [15104][257] f32

    float*  ktvHf = ktvF;
    float*  ktvSf = ktvF + 8L * HD * 256;
    bf16_t* ktvHb = ktvB;
    bf16_t* ktvSb = ktvB + 8L * HD * 256;

    (void)hipMemsetAsync(ktvF, 0, (char*)(ksum + DTOT) - (char*)ktvF, stream);
    (void)hipMemsetAsync(Gfull, 0, 384L * DTOT * 2, stream);

    // ---- weight prep ----
    const unsigned gw = (unsigned)(((long)DTOT * KQP + 255) / 256);
    k_prep_proj<<<gw, 256, 0, stream>>>(Wk, Wkvb);
    k_prep_proj<<<gw, 256, 0, stream>>>(Wv, Wkvb + (long)DTOT * KQP);
    k_prep_proj<<<gw, 256, 0, stream>>>(Wq, Wqb);
    k_prep_ws<<<64, 256, 0, stream>>>(Ws, Wsb);
    k_prep_wh<<<(unsigned)((256L * 2048 + 255) / 256), 256, 0, stream>>>(Wh, Whb);

    GemmP g;

    // ---------------- source phase (2 chunks of 15000) ----------------
    for (int c = 0; c < NCS; ++c) {
        const float* src = source + (long)c * CHS * KIN;
        k_cast_pad<<<(unsigned)(((long)CHS * (KQP / 8) + 255) / 256), 256, 0, stream>>>(src, xcb, CHS);
        // Tk/Tv = (xcb @ Wkvb^T)^T written directly, phi+ksum fused for K-h.
        // grid y covers all CHPS cols (pad cols zeroed here).
        k_mfma_kv<<<dim3((2 * DTOT) / 128, CHPS / 128, 1), 256, 0, stream>>>(
            Wkvb, xcb, Tk, Tv, ksum, CHS);
        k_post_kv_t<<<dim3((CHS + 255) / 256, H), 256, 0, stream>>>(Tk, Tv, ksum, CHS);
        // ktvH_h[k'][v] += sum_n Tk_h[k'][n]*Tv_h[v][n]  (K = 15360, 30 steps/split)
        g = { Tk + (long)SCOL * CHPS, CHPS, (long)HD * CHPS,
              Tv + (long)SCOL * CHPS, CHPS, (long)HD * CHPS,
              ktvHf, 0, 256, (long)HD * 256, 1,  HD, HD, CHPS, KSPLIT };
        k_mfma_nt<128, 128><<<dim3(2, 2, H * KSPLIT), 256, 0, stream>>>(g);
        g = { Tk, CHPS, 32L * CHPS,  Tv, CHPS, 32L * CHPS,
              ktvSf, 0, 32, 32L * 32, 1,  32, 32, CHPS, KSPLIT };
        k_mfma_nt<64, 64><<<dim3(1, 1, H * KSPLIT), 256, 0, stream>>>(g);
    }
    k_castf<<<(unsigned)((8L * (HD * 256 + 32 * 32) + 255) / 256), 256, 0, stream>>>(
        ktvF, ktvB, 8L * (HD * 256 + 32 * 32));

    // ---- fold ktv into output weights: Gfull[o][k] ----
    g = { Wsb, 256, 32,  ktvSb, 32, 32L * 32,  0, Gfull, DTOT, 32, 0,
          SD, 32, 32, 1 };
    k_mfma_nt<64, 64><<<dim3(1, 1, H), 256, 0, stream>>>(g);
    g = { Whb, 2048, 256,  ktvHb, 256, (long)HD * 256,
          0, Gfull + 17L * DTOT + SCOL, DTOT, HD, 0,
          HD, HD, 256, 1 };
    k_mfma_nt<64, 64><<<dim3(4, 4, H), 256, 0, stream>>>(g);

    // ---------------- query phase (2 chunks of 15000) ----------------
    for (int c = 0; c < NCQ; ++c) {
        const float* qsrc = query + (long)c * CHQ * KIN;
        float* orow = out + (long)c * CHQ * 257;
        k_cast_pad<<<(unsigned)(((long)CHQ * (KQP / 8) + 255) / 256), 256, 0, stream>>>(qsrc, xcb, CHQ);
        g = { xcb, KQP, 0,  Wqb, KQP, 0,  0, Yq, DTOT, 0, 0,
              CHQ, DTOT, KQP, 1 };
        k_mfma_nt<128, 128><<<dim3((CHQ + 127) / 128, DTOT / 128, 1), 256, 0, stream>>>(g);
        k_post_q<<<(CHQ * H) / 4, 256, 0, stream>>>(Yq, ksum, CHQ);
        // opre slabs = Yq_scaled @ Gfull^T, K split into OSPLIT windows (exclusive slab stores)
        g = { Yq, DTOT, 0,  Gfull, DTOT, 0,  opre, 0, 257, OSLAB, 3,
              CHQ, 257, DTOT, OSPLIT };
        k_mfma_nt<64, 192><<<dim3((CHQ + 63) / 64, 2, OSPLIT), 256, 0, stream>>>(g);
        k_finalize<<<(CHQ + 3) / 4, 256, 0, stream>>>(opre, orow, CHQ);
    }
}